// Round 15
// baseline (339.080 us; speedup 1.0000x reference)
//
#include <hip/hip_runtime.h>

#define DEPTH 18
#define NN ((1 << DEPTH) - 1)   // 262143

typedef __attribute__((ext_vector_type(8))) short short8;
typedef __attribute__((ext_vector_type(4))) float f32x4;

// fast sigmoid/tanh: v_rcp_f32 (~1e-5 rel err, << bf16 quantum) instead of
// IEEE divide (~10-inst sequence). Saturation exact: rcp(inf)=0, rcp(1)=1.
__device__ __forceinline__ float sigm_(float x) {
    return __builtin_amdgcn_rcpf(1.f + __expf(-x));
}
__device__ __forceinline__ float tanh_(float x) {
    float e = __expf(2.f * x);
    return 1.f - 2.f * __builtin_amdgcn_rcpf(e + 1.f);
}
__device__ __forceinline__ unsigned short f2bf(float f) {
    union { float f; unsigned int u; } v; v.f = f;
    unsigned int r = (v.u + 0x7fffu + ((v.u >> 16) & 1u)) >> 16;
    return (unsigned short)r;
}
__device__ __forceinline__ float bf2f(unsigned short h) {
    union { unsigned int u; float f; } v; v.u = ((unsigned int)h) << 16; return v.f;
}

// ---------------------------------------------------------------------------
// Prep: emb table -> bf16; packed bf16 B matrix.
// bpack layout: [chunk c (8)][col j (512)][k-local (32)], contiguous bf16.
//   chunks 0-3 (x side):  col j<384: Wiou[k][j], j>=384: Wf[k][j-384]
//   chunks 4-7 (h side):  col j<384: Uiou[k][j], j>=384: Uf[k][j-384]
// ---------------------------------------------------------------------------
__global__ void cvt_emb(const float* __restrict__ src, unsigned short* __restrict__ dst, int n4) {
    int i = blockIdx.x * 256 + threadIdx.x;
    if (i < n4) {
        float4 v = ((const float4*)src)[i];
        ushort4 o; o.x = f2bf(v.x); o.y = f2bf(v.y); o.z = f2bf(v.z); o.w = f2bf(v.w);
        ((ushort4*)dst)[i] = o;
    }
}

__global__ void build_bpack(const float* __restrict__ Wiou, const float* __restrict__ Uiou,
                            const float* __restrict__ Wf, const float* __restrict__ Uf,
                            unsigned short* __restrict__ pack) {
    int idx = blockIdx.x * 256 + threadIdx.x;      // 131072 total
    int c = idx >> 14, r = idx & 16383, j = r >> 5, kl = r & 31;
    int k2 = c * 32 + kl;                          // 0..255; <128 = x side
    float v;
    if (j < 384) v = (k2 < 128) ? Wiou[k2 * 384 + j] : Uiou[(k2 - 128) * 384 + j];
    else { int jf = j - 384; v = (k2 < 128) ? Wf[k2 * 128 + jf] : Uf[(k2 - 128) * 128 + jf]; }
    pack[idx] = f2bf(v);
}

#define MM(acc, a, b) acc = __builtin_amdgcn_mfma_f32_16x16x32_bf16(a, b, acc, 0, 0, 0)

// ---------------------------------------------------------------------------
// FUSED leaf(d17)+d16 kernel: 2048 blocks, 256 threads. Block b owns
// parents g0p..g0p+31 (d16) and their 64 children gl0..gl0+63 (contiguous).
// Leaf h/c NEVER go to global: h -> A_s fragment regions 2/3, c -> c_lds.
// Occupancy: 3 blocks/CU (bf16 c_lds 16.9 KB, LDS 52.4 KB, lb(256,3)).
// A elem (region r, node m, k) at r*4096 + ((k>>5)*4 + ((k>>3)&3))*256 + m*8 + (k&7)
// ---------------------------------------------------------------------------
__global__ __launch_bounds__(256, 3) void tree_leaf16_fused(
    const int* __restrict__ xids, const int* __restrict__ msk,
    const unsigned short* __restrict__ embB, const unsigned short* __restrict__ bpack,
    const float* __restrict__ biou, const float* __restrict__ bfv,
    const float* __restrict__ Wout, const float* __restrict__ bout,
    unsigned short* __restrict__ hB, float* __restrict__ c_ws, float* __restrict__ outp)
{
    __shared__ __align__(16) unsigned short A_s[16384];   // 4 regions x 4096, 32 KB
    __shared__ __align__(16) unsigned short c_lds[64][132]; // leaf c (bf16), 16.9 KB
    __shared__ __align__(16) float wout_t[660];           // [5][132] transposed

    const int t   = threadIdx.x;
    const int g0p = 65535 + blockIdx.x * 32;              // parent start (d16)
    const int gl0 = 2 * g0p + 1;                          // leaf start (d17), 64 rows

    if (t < 160) {   // load + transpose Wout
        float4 v = ((const float4*)Wout)[t];
        const int e0 = 4 * t;
        wout_t[((e0    ) % 5) * 132 + (e0    ) / 5] = v.x;
        wout_t[((e0 + 1) % 5) * 132 + (e0 + 1) / 5] = v.y;
        wout_t[((e0 + 2) % 5) * 132 + (e0 + 2) / 5] = v.z;
        wout_t[((e0 + 3) % 5) * 132 + (e0 + 3) / 5] = v.w;
    }

    {   // ---- phase 1: stage leaf emb rows 0-31 -> R0, rows 32-63 -> R1 ----
        const int n = t >> 3, seg = t & 7;
        const int cc = seg >> 1, q0 = (seg & 1) * 2;
        #pragma unroll
        for (int sp = 0; sp < 2; ++sp) {
            const int g = gl0 + sp * 32 + n;
            const int ei = xids[g] * msk[g];
            const uint4* es = (const uint4*)(embB + (size_t)ei * 128 + seg * 16);
            uint4 e0 = es[0], e1 = es[1];
            unsigned short* base = &A_s[sp * 4096];
            *(uint4*)&base[(cc * 4 + q0) * 256 + n * 8]       = e0;
            *(uint4*)&base[(cc * 4 + q0 + 1) * 256 + n * 8]   = e1;
        }
    }
    __syncthreads();

    const int lane = t & 63, w = t >> 6;
    const int ln = lane & 15, q = lane >> 4;
    const unsigned short* bp = bpack + ln * 32 + q * 8;
    const unsigned short* ap = A_s + q * 256 + ln * 8;
    const int ti = 2 * w, to = 8 + 2 * w, tu = 16 + 2 * w, tf = 24 + 2 * w;

#define BF(c, tile) (*(const short8*)(bp + (c) * 16384 + (tile) * 512))
#define AF(r, cc, rt) (*(const short8*)(ap + (r) * 4096 + (cc) * 1024 + (rt) * 128))

    // ---- phases 2,3: two 32-row leaf passes (IOU only, no barrier between:
    //      disjoint A_s reads/writes) ----
    #pragma unroll
    for (int sp = 0; sp < 2; ++sp) {
        f32x4 aI[2][2] = {}, aO[2][2] = {}, aU[2][2] = {};
        #pragma unroll
        for (int c = 0; c < 4; ++c) {
            short8 bI0 = BF(c, ti), bI1 = BF(c, ti + 1);
            short8 bO0 = BF(c, to), bO1 = BF(c, to + 1);
            short8 bU0 = BF(c, tu), bU1 = BF(c, tu + 1);
            short8 aE0 = AF(sp, c, 0), aE1 = AF(sp, c, 1);
            MM(aI[0][0], aE0, bI0); MM(aI[0][1], aE0, bI1);
            MM(aI[1][0], aE1, bI0); MM(aI[1][1], aE1, bI1);
            MM(aO[0][0], aE0, bO0); MM(aO[0][1], aE0, bO1);
            MM(aO[1][0], aE1, bO0); MM(aO[1][1], aE1, bO1);
            MM(aU[0][0], aE0, bU0); MM(aU[0][1], aE0, bU1);
            MM(aU[1][0], aE1, bU0); MM(aU[1][1], aE1, bU1);
        }
        // leaf epilogue: c -> c_lds (bf16), h -> fragment regions 2/3 (reg = 2+(lr&1))
        #pragma unroll
        for (int rt = 0; rt < 2; ++rt) {
            #pragma unroll
            for (int jt = 0; jt < 2; ++jt) {
                const int col = w * 32 + jt * 16 + ln;
                const float bib = biou[col], bob = biou[128 + col], bub = biou[256 + col];
                const int fragoff = ((col >> 5) * 4 + ((col >> 3) & 3)) * 256 + (col & 7);
                #pragma unroll
                for (int r = 0; r < 4; ++r) {
                    const int lr = sp * 32 + rt * 16 + q * 4 + r;   // leaf row 0..63
                    const float iv = aI[rt][jt][r] + bib;
                    const float ov = aO[rt][jt][r] + bob;
                    const float uv = aU[rt][jt][r] + bub;
                    const float cv = sigm_(iv) * tanh_(uv);
                    const float hv = sigm_(ov) * tanh_(cv);
                    c_lds[lr][col] = f2bf(cv);
                    A_s[(2 + (lr & 1)) * 4096 + fragoff + (lr >> 1) * 8] = f2bf(hv);
                }
            }
        }
    }
    __syncthreads();

    {   // ---- phase 4: h_sum (R2+R3 -> R1), parent emb -> R0, leaf out-head ----
        const int m = t >> 3, seg = t & 7;
        const int cc = seg >> 1, q0 = (seg & 1) * 2;
        #pragma unroll
        for (int u = 0; u < 2; ++u) {
            const int idx = (cc * 4 + q0 + u) * 256 + m * 8;
            short8 l = *(short8*)&A_s[2 * 4096 + idx];
            short8 r = *(short8*)&A_s[3 * 4096 + idx];
            short8 s;
            #pragma unroll
            for (int j = 0; j < 8; ++j)
                s[j] = (short)f2bf(bf2f((unsigned short)l[j]) + bf2f((unsigned short)r[j]));
            *(short8*)&A_s[4096 + idx] = s;
        }
        {   // parent emb -> R0 (R0 reads finished in phase 2)
            const int g = g0p + m;
            const int ei = xids[g] * msk[g];
            const uint4* es = (const uint4*)(embB + (size_t)ei * 128 + seg * 16);
            uint4 e0 = es[0], e1 = es[1];
            *(uint4*)&A_s[(cc * 4 + q0) * 256 + m * 8]       = e0;
            *(uint4*)&A_s[(cc * 4 + q0 + 1) * 256 + m * 8]   = e1;
        }
        // leaf out-head: 64 rows x 5 cols = 320 outputs, b128 fragment reads
        for (int o = t; o < 320; o += 256) {
            const int n = o / 5, cc5 = o - 5 * n;
            const int reg = 2 + (n & 1), mm = n >> 1;
            float acc = bout[cc5];
            const unsigned short* hbase = &A_s[reg * 4096 + mm * 8];
            const float* wp = &wout_t[cc5 * 132];
            #pragma unroll
            for (int j = 0; j < 16; ++j) {          // frag slot j holds k = 8j..8j+7
                short8 hv = *(const short8*)(hbase + j * 256);
                const float* wo = wp + j * 8;
                float4 w0 = *(const float4*)(wo);
                float4 w1 = *(const float4*)(wo + 4);
                acc += bf2f((unsigned short)hv[0]) * w0.x + bf2f((unsigned short)hv[1]) * w0.y
                     + bf2f((unsigned short)hv[2]) * w0.z + bf2f((unsigned short)hv[3]) * w0.w
                     + bf2f((unsigned short)hv[4]) * w1.x + bf2f((unsigned short)hv[5]) * w1.y
                     + bf2f((unsigned short)hv[6]) * w1.z + bf2f((unsigned short)hv[7]) * w1.w;
            }
            outp[(size_t)(gl0 + n) * 5 + cc5] = acc;
        }
    }
    __syncthreads();

    // ---- phase 5: full parent (d16) pipeline ----
    f32x4 accI[2][2] = {}, accO[2][2] = {}, accU[2][2] = {}, accFl[2][2] = {}, accFr[2][2] = {};

    #pragma unroll
    for (int c = 0; c < 4; ++c) {      // emb chunks
        short8 bI0 = BF(c, ti), bI1 = BF(c, ti + 1);
        short8 bO0 = BF(c, to), bO1 = BF(c, to + 1);
        short8 bU0 = BF(c, tu), bU1 = BF(c, tu + 1);
        short8 aE0 = AF(0, c, 0), aE1 = AF(0, c, 1);
        MM(accI[0][0], aE0, bI0); MM(accI[0][1], aE0, bI1);
        MM(accI[1][0], aE1, bI0); MM(accI[1][1], aE1, bI1);
        MM(accO[0][0], aE0, bO0); MM(accO[0][1], aE0, bO1);
        MM(accO[1][0], aE1, bO0); MM(accO[1][1], aE1, bO1);
        MM(accU[0][0], aE0, bU0); MM(accU[0][1], aE0, bU1);
        MM(accU[1][0], aE1, bU0); MM(accU[1][1], aE1, bU1);
        short8 bF0 = BF(c, tf), bF1 = BF(c, tf + 1);
        MM(accFl[0][0], aE0, bF0); MM(accFl[0][1], aE0, bF1);
        MM(accFl[1][0], aE1, bF0); MM(accFl[1][1], aE1, bF1);
    }
    #pragma unroll
    for (int rt = 0; rt < 2; ++rt)
        #pragma unroll
        for (int jt = 0; jt < 2; ++jt)
            accFr[rt][jt] = accFl[rt][jt];      // fork shared x_f
    #pragma unroll
    for (int c = 0; c < 4; ++c) {      // h chunks
        short8 bI0 = BF(4 + c, ti), bI1 = BF(4 + c, ti + 1);
        short8 bO0 = BF(4 + c, to), bO1 = BF(4 + c, to + 1);
        short8 bU0 = BF(4 + c, tu), bU1 = BF(4 + c, tu + 1);
        short8 bF0 = BF(4 + c, tf), bF1 = BF(4 + c, tf + 1);
        short8 aH0 = AF(1, c, 0), aH1 = AF(1, c, 1);
        short8 aL0 = AF(2, c, 0), aL1 = AF(2, c, 1);
        short8 aR0 = AF(3, c, 0), aR1 = AF(3, c, 1);
        MM(accI[0][0], aH0, bI0); MM(accI[0][1], aH0, bI1);
        MM(accI[1][0], aH1, bI0); MM(accI[1][1], aH1, bI1);
        MM(accO[0][0], aH0, bO0); MM(accO[0][1], aH0, bO1);
        MM(accO[1][0], aH1, bO0); MM(accO[1][1], aH1, bO1);
        MM(accU[0][0], aH0, bU0); MM(accU[0][1], aH0, bU1);
        MM(accU[1][0], aH1, bU0); MM(accU[1][1], aH1, bU1);
        MM(accFl[0][0], aL0, bF0); MM(accFl[0][1], aL0, bF1);
        MM(accFl[1][0], aL1, bF0); MM(accFl[1][1], aL1, bF1);
        MM(accFr[0][0], aR0, bF0); MM(accFr[0][1], aR0, bF1);
        MM(accFr[1][0], aR1, bF0); MM(accFr[1][1], aR1, bF1);
    }
#undef BF
#undef AF

    __syncthreads();                 // all A_s reads done; reuse as f32 h_s
    float* h_s = (float*)A_s;        // 32 x 132 f32

    #pragma unroll
    for (int rt = 0; rt < 2; ++rt) {
        #pragma unroll
        for (int jt = 0; jt < 2; ++jt) {
            const int col = w * 32 + jt * 16 + ln;
            const float bib = biou[col], bob = biou[128 + col], bub = biou[256 + col];
            const float bfb = bfv[col];
            #pragma unroll
            for (int r = 0; r < 4; ++r) {
                const int row = rt * 16 + q * 4 + r;
                const int g = g0p + row;
                const float iv = accI[rt][jt][r] + bib;
                const float ov = accO[rt][jt][r] + bob;
                const float uv = accU[rt][jt][r] + bub;
                const float fl = sigm_(accFl[rt][jt][r] + bfb);
                const float fr = sigm_(accFr[rt][jt][r] + bfb);
                const float fc = fl * bf2f(c_lds[2 * row][col]) + fr * bf2f(c_lds[2 * row + 1][col]);
                const float cv = sigm_(iv) * tanh_(uv) + fc;
                const float hv = sigm_(ov) * tanh_(cv);
                c_ws[(size_t)g * 128 + col] = cv;
                hB[(size_t)g * 128 + col] = f2bf(hv);
                h_s[row * 132 + col] = hv;
            }
        }
    }
    __syncthreads();
    if (t < 160) {                   // parent out-head
        const int n = t / 5, cc5 = t - 5 * n;
        float acc = bout[cc5];
        const float* hp = &h_s[n * 132];
        const float* wp = &wout_t[cc5 * 132];
        #pragma unroll 4
        for (int k4 = 0; k4 < 32; ++k4) {
            float4 hv = *(const float4*)(hp + 4 * k4);
            float4 wv = *(const float4*)(wp + 4 * k4);
            acc += hv.x * wv.x + hv.y * wv.y + hv.z * wv.z + hv.w * wv.w;
        }
        outp[(size_t)(g0p + n) * 5 + cc5] = acc;
    }
}

// ---------------------------------------------------------------------------
// Big-level MFMA kernel (d = 15..10).  R15: lb (256,2)->(256,3) — same
// occupancy lever verified on the fused kernel in R9/R10 (identical 20x
// f32x4 acc structure; 88 arch + 80 acc = 168 <= 170 reg budget;
// LDS 35.8KB x 3 = 107KB <= 160KB -> 3 blocks/CU).
// ---------------------------------------------------------------------------
template<int HC>
__global__ __launch_bounds__(256, 3) void tree_level_mfma(
    const int* __restrict__ xids, const int* __restrict__ msk,
    const unsigned short* __restrict__ embB, const unsigned short* __restrict__ bpack,
    const float* __restrict__ biou, const float* __restrict__ bfv,
    const float* __restrict__ Wout, const float* __restrict__ bout,
    unsigned short* __restrict__ hB, float* __restrict__ c_ws, float* __restrict__ outp,
    int s0)
{
    __shared__ __align__(16) unsigned short A_s[16384];   // 4 x 4096, 32 KB
    __shared__ __align__(16) float wout_t[660];           // [5][132] transposed, padded

    const int t  = threadIdx.x;
    const int g0 = s0 + blockIdx.x * 32;

    if (t < 160) {   // load + transpose Wout (row-major [k][5] -> [c][132])
        float4 v = ((const float4*)Wout)[t];
        const int e0 = 4 * t;
        wout_t[((e0    ) % 5) * 132 + (e0    ) / 5] = v.x;
        wout_t[((e0 + 1) % 5) * 132 + (e0 + 1) / 5] = v.y;
        wout_t[((e0 + 2) % 5) * 132 + (e0 + 2) / 5] = v.z;
        wout_t[((e0 + 3) % 5) * 132 + (e0 + 3) / 5] = v.w;
    }

    {   // ---- stage emb (region 0) ----
        const int n = t >> 3, seg = t & 7;
        const int g = g0 + n;
        const int ei = xids[g] * msk[g];
        const uint4* es = (const uint4*)(embB + (size_t)ei * 128 + seg * 16);
        uint4 e0 = es[0], e1 = es[1];
        const int cc = seg >> 1, q0 = (seg & 1) * 2;
        *(uint4*)&A_s[(cc * 4 + q0) * 256 + n * 8]       = e0;
        *(uint4*)&A_s[(cc * 4 + q0 + 1) * 256 + n * 8]   = e1;
        if (HC) {    // ---- stage h_l / h_r (regions 2,3) ----
            const int row = t >> 2, qt = t & 3;
            const int child = 2 * g0 + 1 + row;
            const int m = row >> 1, reg = 2 + (row & 1);
            const uint4* hp = (const uint4*)(hB + (size_t)child * 128 + qt * 32);
            uint4 p0 = hp[0], p1 = hp[1], p2 = hp[2], p3 = hp[3];
            unsigned short* base = &A_s[reg * 4096 + qt * 1024 + m * 8];
            *(uint4*)(base)       = p0;
            *(uint4*)(base + 256) = p1;
            *(uint4*)(base + 512) = p2;
            *(uint4*)(base + 768) = p3;
        }
    }

    const int lane = t & 63, w = t >> 6;
    const int ln = lane & 15, q = lane >> 4;

    // ---- prefetch child c cells for the epilogue (fire-and-forget) ----
    float clp[2][2][4], crp[2][2][4];
    if (HC) {
        #pragma unroll
        for (int rt = 0; rt < 2; ++rt)
            #pragma unroll
            for (int jt = 0; jt < 2; ++jt) {
                const int col = w * 32 + jt * 16 + ln;
                #pragma unroll
                for (int r = 0; r < 4; ++r) {
                    const int g = g0 + rt * 16 + q * 4 + r;
                    clp[rt][jt][r] = c_ws[(size_t)(2 * g + 1) * 128 + col];
                    crp[rt][jt][r] = c_ws[(size_t)(2 * g + 2) * 128 + col];
                }
            }
    }

    if (HC) {        // ---- h_sum = h_l + h_r (region 1), in-LDS ----
        __syncthreads();
        const int m = t >> 3, seg = t & 7;
        const int cc = seg >> 1, q0 = (seg & 1) * 2;
        #pragma unroll
        for (int u = 0; u < 2; ++u) {
            const int idx = (cc * 4 + q0 + u) * 256 + m * 8;
            short8 l = *(short8*)&A_s[2 * 4096 + idx];
            short8 r = *(short8*)&A_s[3 * 4096 + idx];
            short8 s;
            #pragma unroll
            for (int j = 0; j < 8; ++j)
                s[j] = (short)f2bf(bf2f((unsigned short)l[j]) + bf2f((unsigned short)r[j]));
            *(short8*)&A_s[4096 + idx] = s;
        }
    }
    __syncthreads();

    const unsigned short* bp = bpack + ln * 32 + q * 8;     // + c*16384 + tile*512
    const unsigned short* ap = A_s + q * 256 + ln * 8;      // + r*4096 + cc*1024 + rt*128

#define BF(c, tile) (*(const short8*)(bp + (c) * 16384 + (tile) * 512))
#define AF(r, cc, rt) (*(const short8*)(ap + (r) * 4096 + (cc) * 1024 + (rt) * 128))

    f32x4 accI[2][2] = {}, accO[2][2] = {}, accU[2][2] = {}, accFl[2][2] = {}, accFr[2][2] = {};
    const int ti = 2 * w, to = 8 + 2 * w, tu = 16 + 2 * w, tf = 24 + 2 * w;

    #pragma unroll
    for (int c = 0; c < 4; ++c) {      // emb chunks
        short8 bI0 = BF(c, ti), bI1 = BF(c, ti + 1);
        short8 bO0 = BF(c, to), bO1 = BF(c, to + 1);
        short8 bU0 = BF(c, tu), bU1 = BF(c, tu + 1);
        short8 aE0 = AF(0, c, 0), aE1 = AF(0, c, 1);
        MM(accI[0][0], aE0, bI0); MM(accI[0][1], aE0, bI1);
        MM(accI[1][0], aE1, bI0); MM(accI[1][1], aE1, bI1);
        MM(accO[0][0], aE0, bO0); MM(accO[0][1], aE0, bO1);
        MM(accO[1][0], aE1, bO0); MM(accO[1][1], aE1, bO1);
        MM(accU[0][0], aE0, bU0); MM(accU[0][1], aE0, bU1);
        MM(accU[1][0], aE1, bU0); MM(accU[1][1], aE1, bU1);
        if (HC) {
            short8 bF0 = BF(c, tf), bF1 = BF(c, tf + 1);
            MM(accFl[0][0], aE0, bF0); MM(accFl[0][1], aE0, bF1);
            MM(accFl[1][0], aE1, bF0); MM(accFl[1][1], aE1, bF1);
        }
    }
    if (HC) {
        #pragma unroll
        for (int rt = 0; rt < 2; ++rt)
            #pragma unroll
            for (int jt = 0; jt < 2; ++jt)
                accFr[rt][jt] = accFl[rt][jt];      // fork shared x_f
        #pragma unroll
        for (int c = 0; c < 4; ++c) {  // h chunks (bpack chunk 4+c)
            short8 bI0 = BF(4 + c, ti), bI1 = BF(4 + c, ti + 1);
            short8 bO0 = BF(4 + c, to), bO1 = BF(4 + c, to + 1);
            short8 bU0 = BF(4 + c, tu), bU1 = BF(4 + c, tu + 1);
            short8 bF0 = BF(4 + c, tf), bF1 = BF(4 + c, tf + 1);
            short8 aH0 = AF(1, c, 0), aH1 = AF(1, c, 1);
            short8 aL0 = AF(2, c, 0), aL1 = AF(2, c, 1);
            short8 aR0 = AF(3, c, 0), aR1 = AF(3, c, 1);
            MM(accI[0][0], aH0, bI0); MM(accI[0][1], aH0, bI1);
            MM(accI[1][0], aH1, bI0); MM(accI[1][1], aH1, bI1);
            MM(accO[0][0], aH0, bO0); MM(accO[0][1], aH0, bO1);
            MM(accO[1][0], aH1, bO0); MM(accO[1][1], aH1, bO1);
            MM(accU[0][0], aH0, bU0); MM(accU[0][1], aH0, bU1);
            MM(accU[1][0], aH1, bU0); MM(accU[1][1], aH1, bU1);
            MM(accFl[0][0], aL0, bF0); MM(accFl[0][1], aL0, bF1);
            MM(accFl[1][0], aL1, bF0); MM(accFl[1][1], aL1, bF1);
            MM(accFr[0][0], aR0, bF0); MM(accFr[0][1], aR0, bF1);
            MM(accFr[1][0], aR1, bF0); MM(accFr[1][1], aR1, bF1);
        }
    }
#undef BF
#undef AF

    __syncthreads();                 // all A_s reads done; reuse as f32 h_s
    float* h_s = (float*)A_s;        // 32 x 132 f32 (16.9 KB <= 32 KB)

    #pragma unroll
    for (int rt = 0; rt < 2; ++rt) {
        #pragma unroll
        for (int jt = 0; jt < 2; ++jt) {
            const int col = w * 32 + jt * 16 + ln;
            const float bib = biou[col], bob = biou[128 + col], bub = biou[256 + col];
            const float bfb = bfv[col];
            #pragma unroll
            for (int r = 0; r < 4; ++r) {
                const int row = rt * 16 + q * 4 + r;
                const int g = g0 + row;
                const float iv = accI[rt][jt][r] + bib;
                const float ov = accO[rt][jt][r] + bob;
                const float uv = accU[rt][jt][r] + bub;
                float fc = 0.f;
                if (HC) {
                    const float fl = sigm_(accFl[rt][jt][r] + bfb);
                    const float fr = sigm_(accFr[rt][jt][r] + bfb);
                    fc = fl * clp[rt][jt][r] + fr * crp[rt][jt][r];
                }
                const float cc = sigm_(iv) * tanh_(uv) + fc;
                const float hh = sigm_(ov) * tanh_(cc);
                c_ws[(size_t)g * 128 + col] = cc;
                hB[(size_t)g * 128 + col] = f2bf(hh);
                h_s[row * 132 + col] = hh;
            }
        }
    }
    __syncthreads();
    if (t < 160) {                   // output head: 32 nodes x 5 cols, f32, b128 reads
        const int n = t / 5, cc5 = t - 5 * n;
        float acc = bout[cc5];
        const float* hp = &h_s[n * 132];
        const float* wp = &wout_t[cc5 * 132];
        #pragma unroll 4
        for (int k4 = 0; k4 < 32; ++k4) {
            float4 hv = *(const float4*)(hp + 4 * k4);
            float4 wv = *(const float4*)(wp + 4 * k4);
            acc += hv.x * wv.x + hv.y * wv.y + hv.z * wv.z + hv.w * wv.w;
        }
        outp[(size_t)(g0 + n) * 5 + cc5] = acc;
    }
}

// ---------------------------------------------------------------------------
// Subtree kernel: unchanged verified structure.
// ---------------------------------------------------------------------------
__global__ __launch_bounds__(256) void tree_subtree(
    const int* __restrict__ xids, const int* __restrict__ msk,
    const unsigned short* __restrict__ embB, const unsigned short* __restrict__ bpack,
    const float* __restrict__ biou, const float* __restrict__ bfv,
    const float* __restrict__ Wout, const float* __restrict__ bout,
    unsigned short* __restrict__ hB, float* __restrict__ c_ws, float* __restrict__ outp,
    int dTop, int dBot)
{
    __shared__ __align__(16) unsigned short A_s[6144];    // 3 x 2048, 12 KB
    __shared__ __align__(16) float cbuf[2][16][128];      // 16 KB
    __shared__ __align__(16) float wout_t[5][132];        // transposed, padded

    const int t = threadIdx.x, b = blockIdx.x;
    const int lane = t & 63, w = t >> 6;
    const int ln = lane & 15, q = lane >> 4;

    if (t < 160) {   // load + transpose Wout
        float4 v = ((const float4*)Wout)[t];
        const int e0 = 4 * t;
        wout_t[(e0    ) % 5][(e0    ) / 5] = v.x;
        wout_t[(e0 + 1) % 5][(e0 + 1) / 5] = v.y;
        wout_t[(e0 + 2) % 5][(e0 + 2) / 5] = v.z;
        wout_t[(e0 + 3) % 5][(e0 + 3) / 5] = v.w;
    }

    const int col0 = w * 32 + ln, col1 = col0 + 16;
    const float bib0 = biou[col0], bob0 = biou[128 + col0], bub0 = biou[256 + col0], bfb0 = bfv[col0];
    const float bib1 = biou[col1], bob1 = biou[128 + col1], bub1 = biou[256 + col1], bfb1 = bfv[col1];

    const unsigned short* bp = bpack + ln * 32 + q * 8;
    const unsigned short* ap = A_s + (q * 16 + ln) * 8;
    const int ti = 2 * w, to = 8 + 2 * w, tu = 16 + 2 * w, tf = 24 + 2 * w;

    for (int d = dTop; d >= dBot; --d) {
        const int nd = 1 << (d - dBot);
        const int g0 = ((1 << d) - 1) + (b << (d - dBot));
        const int par = (dTop - d) & 1;

        if (t < 128) {   // stage emb (region 0), 16 rows (garbage rows >= nd ok)
            const int m = t >> 3, seg = t & 7;
            const int g = g0 + m;
            const int ei = xids[g] * msk[g];
            const uint4* es = (const uint4*)(embB + (size_t)ei * 128 + seg * 16);
            uint4 e0 = es[0], e1 = es[1];
            const int cc = seg >> 1, q0 = (seg & 1) * 2;
            *(uint4*)&A_s[cc * 512 + (q0 * 16 + m) * 8]       = e0;
            *(uint4*)&A_s[cc * 512 + ((q0 + 1) * 16 + m) * 8] = e1;
        }
        if (d == dTop) {   // stage 32 child h rows from global
            const int row = t >> 3, sg = t & 7;
            const int child = 2 * g0 + 1 + row;
            const uint4* hp = (const uint4*)(hB + (size_t)child * 128 + sg * 16);
            uint4 h0 = hp[0], h1 = hp[1];
            const int reg = 1 + (row & 1), mm = row >> 1;
            const int cc = sg >> 1, q0 = (sg & 1) * 2;
            *(uint4*)&A_s[reg * 2048 + cc * 512 + (q0 * 16 + mm) * 8]       = h0;
            *(uint4*)&A_s[reg * 2048 + cc * 512 + ((q0 + 1) * 16 + mm) * 8] = h1;
        }
        __syncthreads();

        f32x4 accI[2] = {}, accO[2] = {}, accU[2] = {}, accFl[2] = {}, accFr[2] = {};
#define BF1(c, tile) (*(const short8*)(bp + (c) * 16384 + (tile) * 512))
#define AF1(r, c) (*(const short8*)(ap + (r) * 2048 + (c) * 512))
        #pragma unroll
        for (int c = 0; c < 4; ++c) {
            short8 aE = AF1(0, c);
            MM(accI[0], aE, BF1(c, ti)); MM(accI[1], aE, BF1(c, ti + 1));
            MM(accO[0], aE, BF1(c, to)); MM(accO[1], aE, BF1(c, to + 1));
            MM(accU[0], aE, BF1(c, tu)); MM(accU[1], aE, BF1(c, tu + 1));
            MM(accFl[0], aE, BF1(c, tf)); MM(accFl[1], aE, BF1(c, tf + 1));
        }
        accFr[0] = accFl[0]; accFr[1] = accFl[1];
        #pragma unroll
        for (int c = 0; c < 4; ++c) {
            short8 aL = AF1(1, c), aR = AF1(2, c);
            short8 bI0 = BF1(4 + c, ti), bI1 = BF1(4 + c, ti + 1);
            short8 bO0 = BF1(4 + c, to), bO1 = BF1(4 + c, to + 1);
            short8 bU0 = BF1(4 + c, tu), bU1 = BF1(4 + c, tu + 1);
            short8 bF0 = BF1(4 + c, tf), bF1 = BF1(4 + c, tf + 1);
            MM(accI[0], aL, bI0); MM(accI[0], aR, bI0);
            MM(accI[1], aL, bI1); MM(accI[1], aR, bI1);
            MM(accO[0], aL, bO0); MM(accO[0], aR, bO0);
            MM(accO[1], aL, bO1); MM(accO[1], aR, bO1);
            MM(accU[0], aL, bU0); MM(accU[0], aR, bU0);
            MM(accU[1], aL, bU1); MM(accU[1], aR, bU1);
            MM(accFl[0], aL, bF0); MM(accFl[1], aL, bF1);
            MM(accFr[0], aR, bF0); MM(accFr[1], aR, bF1);
        }
#undef BF1
#undef AF1
        __syncthreads();   // k-loop reads done before epilogue overwrites A_s h

        #pragma unroll
        for (int jt = 0; jt < 2; ++jt) {
            const int col = jt ? col1 : col0;
            const float bib = jt ? bib1 : bib0, bob = jt ? bob1 : bob0;
            const float bub = jt ? bub1 : bub0, bfb = jt ? bfb1 : bfb0;
            const f32x4 aI = accI[jt], aO = accO[jt], aU = accU[jt];
            const f32x4 aFl = accFl[jt], aFr = accFr[jt];
            #pragma unroll
            for (int r = 0; r < 4; ++r) {
                const int row = q * 4 + r;
                const int g = g0 + row;
                float cl, cr;
                if (d == dTop) {
                    cl = c_ws[(size_t)(2 * g + 1) * 128 + col];
                    cr = c_ws[(size_t)(2 * g + 2) * 128 + col];
                } else {
                    cl = cbuf[1 - par][2 * row][col];
                    cr = cbuf[1 - par][2 * row + 1][col];
                }
                const float iv = aI[r] + bib;
                const float ov = aO[r] + bob;
                const float uv = aU[r] + bub;
                const float fl = sigm_(aFl[r] + bfb);
                const float fr = sigm_(aFr[r] + bfb);
                const float cc = sigm_(iv) * tanh_(uv) + fl * cl + fr * cr;
                const float hh = sigm_(ov) * tanh_(cc);
                cbuf[par][row][col] = cc;
                const unsigned short hb = f2bf(hh);
                const int reg = 1 + (row & 1), mm = row >> 1;
                A_s[reg * 2048 + (col >> 5) * 512 + ((((col >> 3) & 3) * 16) + mm) * 8 + (col & 7)] = hb;
                if (row < nd) {
                    c_ws[(size_t)g * 128 + col] = cc;
                    hB[(size_t)g * 128 + col] = hb;
                }
            }
        }
        __syncthreads();
        if (t < nd * 5) {            // output head: b128 octet reads of fragment h
            const int n = t / 5, cc5 = t - 5 * n;
            const int reg = 1 + (n & 1), mm = n >> 1;
            float acc = bout[cc5];
            const unsigned short* hbase = &A_s[reg * 2048 + mm * 8];
            const float* wp = wout_t[cc5];
            #pragma unroll
            for (int oct = 0; oct < 16; ++oct) {
                short8 hv = *(const short8*)(hbase + (oct >> 2) * 512 + (oct & 3) * 128);
                const float* wo = wp + oct * 8;
                float4 w0 = *(const float4*)(wo);
                float4 w1 = *(const float4*)(wo + 4);
                acc += bf2f((unsigned short)hv[0]) * w0.x + bf2f((unsigned short)hv[1]) * w0.y
                     + bf2f((unsigned short)hv[2]) * w0.z + bf2f((unsigned short)hv[3]) * w0.w
                     + bf2f((unsigned short)hv[4]) * w1.x + bf2f((unsigned short)hv[5]) * w1.y
                     + bf2f((unsigned short)hv[6]) * w1.z + bf2f((unsigned short)hv[7]) * w1.w;
            }
            outp[(size_t)(g0 + n) * 5 + cc5] = acc;
        }
        __syncthreads();
    }
}
#undef MM

extern "C" void kernel_launch(void* const* d_in, const int* in_sizes, int n_in,
                              void* d_out, int out_size, void* d_ws, size_t ws_size,
                              hipStream_t stream)
{
    (void)in_sizes; (void)n_in; (void)out_size; (void)ws_size;
    const int*   xids = (const int*)d_in[0];
    const int*   msk  = (const int*)d_in[1];
    const float* emb  = (const float*)d_in[2];
    const float* Wiou = (const float*)d_in[3];
    const float* Uiou = (const float*)d_in[4];
    const float* biou = (const float*)d_in[5];
    const float* Wf   = (const float*)d_in[6];
    const float* Uf   = (const float*)d_in[7];
    const float* bfv  = (const float*)d_in[8];
    const float* Wout = (const float*)d_in[9];
    const float* bout = (const float*)d_in[10];
    float* outp = (float*)d_out;

    // workspace: embB (8.2MB) | bpack (0.26MB) | hB (67MB) | c_ws f32 (134MB)
    unsigned short* embB  = (unsigned short*)d_ws;
    unsigned short* bpack = embB + (size_t)32000 * 128;
    unsigned short* hB    = bpack + 131072;
    float*          c_ws  = (float*)(hB + (size_t)NN * 128);

    cvt_emb<<<dim3((32000 * 128 / 4 + 255) / 256), dim3(256), 0, stream>>>(emb, embB, 32000 * 128 / 4);
    build_bpack<<<dim3(131072 / 256), dim3(256), 0, stream>>>(Wiou, Uiou, Wf, Uf, bpack);

    // fused leaf (d17) + d16: leaf h/c stay in LDS, no global round-trip
    tree_leaf16_fused<<<dim3(2048), dim3(256), 0, stream>>>(
        xids, msk, embB, bpack, biou, bfv, Wout, bout, hB, c_ws, outp);

    for (int d = DEPTH - 3; d >= 10; --d) {
        const int s0 = (1 << d) - 1;
        tree_level_mfma<1><<<dim3((1 << d) / 32), dim3(256), 0, stream>>>(
            xids, msk, embB, bpack, biou, bfv, Wout, bout, hB, c_ws, outp, s0);
    }
    // levels 9..5: 32 subtree blocks; levels 4..0: 1 subtree block
    tree_subtree<<<dim3(32), dim3(256), 0, stream>>>(
        xids, msk, embB, bpack, biou, bfv, Wout, bout, hB, c_ws, outp, 9, 5);
    tree_subtree<<<dim3(1), dim3(256), 0, stream>>>(
        xids, msk, embB, bpack, biou, bfv, Wout, bout, hB, c_ws, outp, 4, 0);
}

// Round 17
// 332.857 us; speedup vs baseline: 1.0187x; 1.0187x over previous
//
#include <hip/hip_runtime.h>

#define DEPTH 18
#define NN ((1 << DEPTH) - 1)   // 262143

typedef __attribute__((ext_vector_type(8))) short short8;
typedef __attribute__((ext_vector_type(4))) float f32x4;

// fast sigmoid/tanh: v_rcp_f32 (~1e-5 rel err, << bf16 quantum) instead of
// IEEE divide (~10-inst sequence). Saturation exact: rcp(inf)=0, rcp(1)=1.
__device__ __forceinline__ float sigm_(float x) {
    return __builtin_amdgcn_rcpf(1.f + __expf(-x));
}
__device__ __forceinline__ float tanh_(float x) {
    float e = __expf(2.f * x);
    return 1.f - 2.f * __builtin_amdgcn_rcpf(e + 1.f);
}
__device__ __forceinline__ unsigned short f2bf(float f) {
    union { float f; unsigned int u; } v; v.f = f;
    unsigned int r = (v.u + 0x7fffu + ((v.u >> 16) & 1u)) >> 16;
    return (unsigned short)r;
}
__device__ __forceinline__ float bf2f(unsigned short h) {
    union { unsigned int u; float f; } v; v.u = ((unsigned int)h) << 16; return v.f;
}

// ---------------------------------------------------------------------------
// Prep: emb table -> bf16; packed bf16 B matrix.
// bpack layout: [chunk c (8)][col j (512)][k-local (32)], contiguous bf16.
//   chunks 0-3 (x side):  col j<384: Wiou[k][j], j>=384: Wf[k][j-384]
//   chunks 4-7 (h side):  col j<384: Uiou[k][j], j>=384: Uf[k][j-384]
// ---------------------------------------------------------------------------
__global__ void cvt_emb(const float* __restrict__ src, unsigned short* __restrict__ dst, int n4) {
    int i = blockIdx.x * 256 + threadIdx.x;
    if (i < n4) {
        float4 v = ((const float4*)src)[i];
        ushort4 o; o.x = f2bf(v.x); o.y = f2bf(v.y); o.z = f2bf(v.z); o.w = f2bf(v.w);
        ((ushort4*)dst)[i] = o;
    }
}

__global__ void build_bpack(const float* __restrict__ Wiou, const float* __restrict__ Uiou,
                            const float* __restrict__ Wf, const float* __restrict__ Uf,
                            unsigned short* __restrict__ pack) {
    int idx = blockIdx.x * 256 + threadIdx.x;      // 131072 total
    int c = idx >> 14, r = idx & 16383, j = r >> 5, kl = r & 31;
    int k2 = c * 32 + kl;                          // 0..255; <128 = x side
    float v;
    if (j < 384) v = (k2 < 128) ? Wiou[k2 * 384 + j] : Uiou[(k2 - 128) * 384 + j];
    else { int jf = j - 384; v = (k2 < 128) ? Wf[k2 * 128 + jf] : Uf[(k2 - 128) * 128 + jf]; }
    pack[idx] = f2bf(v);
}

#define MM(acc, a, b) acc = __builtin_amdgcn_mfma_f32_16x16x32_bf16(a, b, acc, 0, 0, 0)

// ---------------------------------------------------------------------------
// FUSED leaf(d17)+d16 kernel: 2048 blocks, 256 threads. Block b owns
// parents g0p..g0p+31 (d16) and their 64 children gl0..gl0+63 (contiguous).
// Leaf h/c NEVER go to global: h -> A_s fragment regions 2/3, c -> c_lds.
// Occupancy: 3 blocks/CU (bf16 c_lds 16.9 KB, LDS 52.4 KB, lb(256,3)).
// A elem (region r, node m, k) at r*4096 + ((k>>5)*4 + ((k>>3)&3))*256 + m*8 + (k&7)
// ---------------------------------------------------------------------------
__global__ __launch_bounds__(256, 3) void tree_leaf16_fused(
    const int* __restrict__ xids, const int* __restrict__ msk,
    const unsigned short* __restrict__ embB, const unsigned short* __restrict__ bpack,
    const float* __restrict__ biou, const float* __restrict__ bfv,
    const float* __restrict__ Wout, const float* __restrict__ bout,
    unsigned short* __restrict__ hB, float* __restrict__ c_ws, float* __restrict__ outp)
{
    __shared__ __align__(16) unsigned short A_s[16384];   // 4 regions x 4096, 32 KB
    __shared__ __align__(16) unsigned short c_lds[64][132]; // leaf c (bf16), 16.9 KB
    __shared__ __align__(16) float wout_t[660];           // [5][132] transposed

    const int t   = threadIdx.x;
    const int g0p = 65535 + blockIdx.x * 32;              // parent start (d16)
    const int gl0 = 2 * g0p + 1;                          // leaf start (d17), 64 rows

    if (t < 160) {   // load + transpose Wout
        float4 v = ((const float4*)Wout)[t];
        const int e0 = 4 * t;
        wout_t[((e0    ) % 5) * 132 + (e0    ) / 5] = v.x;
        wout_t[((e0 + 1) % 5) * 132 + (e0 + 1) / 5] = v.y;
        wout_t[((e0 + 2) % 5) * 132 + (e0 + 2) / 5] = v.z;
        wout_t[((e0 + 3) % 5) * 132 + (e0 + 3) / 5] = v.w;
    }

    {   // ---- phase 1: stage leaf emb rows 0-31 -> R0, rows 32-63 -> R1 ----
        const int n = t >> 3, seg = t & 7;
        const int cc = seg >> 1, q0 = (seg & 1) * 2;
        #pragma unroll
        for (int sp = 0; sp < 2; ++sp) {
            const int g = gl0 + sp * 32 + n;
            const int ei = xids[g] * msk[g];
            const uint4* es = (const uint4*)(embB + (size_t)ei * 128 + seg * 16);
            uint4 e0 = es[0], e1 = es[1];
            unsigned short* base = &A_s[sp * 4096];
            *(uint4*)&base[(cc * 4 + q0) * 256 + n * 8]       = e0;
            *(uint4*)&base[(cc * 4 + q0 + 1) * 256 + n * 8]   = e1;
        }
    }
    __syncthreads();

    const int lane = t & 63, w = t >> 6;
    const int ln = lane & 15, q = lane >> 4;
    const unsigned short* bp = bpack + ln * 32 + q * 8;
    const unsigned short* ap = A_s + q * 256 + ln * 8;
    const int ti = 2 * w, to = 8 + 2 * w, tu = 16 + 2 * w, tf = 24 + 2 * w;

#define BF(c, tile) (*(const short8*)(bp + (c) * 16384 + (tile) * 512))
#define AF(r, cc, rt) (*(const short8*)(ap + (r) * 4096 + (cc) * 1024 + (rt) * 128))

    // ---- phases 2,3: two 32-row leaf passes (IOU only, no barrier between:
    //      disjoint A_s reads/writes) ----
    #pragma unroll
    for (int sp = 0; sp < 2; ++sp) {
        f32x4 aI[2][2] = {}, aO[2][2] = {}, aU[2][2] = {};
        #pragma unroll
        for (int c = 0; c < 4; ++c) {
            short8 bI0 = BF(c, ti), bI1 = BF(c, ti + 1);
            short8 bO0 = BF(c, to), bO1 = BF(c, to + 1);
            short8 bU0 = BF(c, tu), bU1 = BF(c, tu + 1);
            short8 aE0 = AF(sp, c, 0), aE1 = AF(sp, c, 1);
            MM(aI[0][0], aE0, bI0); MM(aI[0][1], aE0, bI1);
            MM(aI[1][0], aE1, bI0); MM(aI[1][1], aE1, bI1);
            MM(aO[0][0], aE0, bO0); MM(aO[0][1], aE0, bO1);
            MM(aO[1][0], aE1, bO0); MM(aO[1][1], aE1, bO1);
            MM(aU[0][0], aE0, bU0); MM(aU[0][1], aE0, bU1);
            MM(aU[1][0], aE1, bU0); MM(aU[1][1], aE1, bU1);
        }
        // leaf epilogue: c -> c_lds (bf16), h -> fragment regions 2/3 (reg = 2+(lr&1))
        #pragma unroll
        for (int rt = 0; rt < 2; ++rt) {
            #pragma unroll
            for (int jt = 0; jt < 2; ++jt) {
                const int col = w * 32 + jt * 16 + ln;
                const float bib = biou[col], bob = biou[128 + col], bub = biou[256 + col];
                const int fragoff = ((col >> 5) * 4 + ((col >> 3) & 3)) * 256 + (col & 7);
                #pragma unroll
                for (int r = 0; r < 4; ++r) {
                    const int lr = sp * 32 + rt * 16 + q * 4 + r;   // leaf row 0..63
                    const float iv = aI[rt][jt][r] + bib;
                    const float ov = aO[rt][jt][r] + bob;
                    const float uv = aU[rt][jt][r] + bub;
                    const float cv = sigm_(iv) * tanh_(uv);
                    const float hv = sigm_(ov) * tanh_(cv);
                    c_lds[lr][col] = f2bf(cv);
                    A_s[(2 + (lr & 1)) * 4096 + fragoff + (lr >> 1) * 8] = f2bf(hv);
                }
            }
        }
    }
    __syncthreads();

    {   // ---- phase 4: h_sum (R2+R3 -> R1), parent emb -> R0, leaf out-head ----
        const int m = t >> 3, seg = t & 7;
        const int cc = seg >> 1, q0 = (seg & 1) * 2;
        #pragma unroll
        for (int u = 0; u < 2; ++u) {
            const int idx = (cc * 4 + q0 + u) * 256 + m * 8;
            short8 l = *(short8*)&A_s[2 * 4096 + idx];
            short8 r = *(short8*)&A_s[3 * 4096 + idx];
            short8 s;
            #pragma unroll
            for (int j = 0; j < 8; ++j)
                s[j] = (short)f2bf(bf2f((unsigned short)l[j]) + bf2f((unsigned short)r[j]));
            *(short8*)&A_s[4096 + idx] = s;
        }
        {   // parent emb -> R0 (R0 reads finished in phase 2)
            const int g = g0p + m;
            const int ei = xids[g] * msk[g];
            const uint4* es = (const uint4*)(embB + (size_t)ei * 128 + seg * 16);
            uint4 e0 = es[0], e1 = es[1];
            *(uint4*)&A_s[(cc * 4 + q0) * 256 + m * 8]       = e0;
            *(uint4*)&A_s[(cc * 4 + q0 + 1) * 256 + m * 8]   = e1;
        }
        // leaf out-head: 64 rows x 5 cols = 320 outputs, b128 fragment reads
        for (int o = t; o < 320; o += 256) {
            const int n = o / 5, cc5 = o - 5 * n;
            const int reg = 2 + (n & 1), mm = n >> 1;
            float acc = bout[cc5];
            const unsigned short* hbase = &A_s[reg * 4096 + mm * 8];
            const float* wp = &wout_t[cc5 * 132];
            #pragma unroll
            for (int j = 0; j < 16; ++j) {          // frag slot j holds k = 8j..8j+7
                short8 hv = *(const short8*)(hbase + j * 256);
                const float* wo = wp + j * 8;
                float4 w0 = *(const float4*)(wo);
                float4 w1 = *(const float4*)(wo + 4);
                acc += bf2f((unsigned short)hv[0]) * w0.x + bf2f((unsigned short)hv[1]) * w0.y
                     + bf2f((unsigned short)hv[2]) * w0.z + bf2f((unsigned short)hv[3]) * w0.w
                     + bf2f((unsigned short)hv[4]) * w1.x + bf2f((unsigned short)hv[5]) * w1.y
                     + bf2f((unsigned short)hv[6]) * w1.z + bf2f((unsigned short)hv[7]) * w1.w;
            }
            outp[(size_t)(gl0 + n) * 5 + cc5] = acc;
        }
    }
    __syncthreads();

    // ---- phase 5: full parent (d16) pipeline ----
    f32x4 accI[2][2] = {}, accO[2][2] = {}, accU[2][2] = {}, accFl[2][2] = {}, accFr[2][2] = {};

    #pragma unroll
    for (int c = 0; c < 4; ++c) {      // emb chunks
        short8 bI0 = BF(c, ti), bI1 = BF(c, ti + 1);
        short8 bO0 = BF(c, to), bO1 = BF(c, to + 1);
        short8 bU0 = BF(c, tu), bU1 = BF(c, tu + 1);
        short8 aE0 = AF(0, c, 0), aE1 = AF(0, c, 1);
        MM(accI[0][0], aE0, bI0); MM(accI[0][1], aE0, bI1);
        MM(accI[1][0], aE1, bI0); MM(accI[1][1], aE1, bI1);
        MM(accO[0][0], aE0, bO0); MM(accO[0][1], aE0, bO1);
        MM(accO[1][0], aE1, bO0); MM(accO[1][1], aE1, bO1);
        MM(accU[0][0], aE0, bU0); MM(accU[0][1], aE0, bU1);
        MM(accU[1][0], aE1, bU0); MM(accU[1][1], aE1, bU1);
        short8 bF0 = BF(c, tf), bF1 = BF(c, tf + 1);
        MM(accFl[0][0], aE0, bF0); MM(accFl[0][1], aE0, bF1);
        MM(accFl[1][0], aE1, bF0); MM(accFl[1][1], aE1, bF1);
    }
    #pragma unroll
    for (int rt = 0; rt < 2; ++rt)
        #pragma unroll
        for (int jt = 0; jt < 2; ++jt)
            accFr[rt][jt] = accFl[rt][jt];      // fork shared x_f
    #pragma unroll
    for (int c = 0; c < 4; ++c) {      // h chunks
        short8 bI0 = BF(4 + c, ti), bI1 = BF(4 + c, ti + 1);
        short8 bO0 = BF(4 + c, to), bO1 = BF(4 + c, to + 1);
        short8 bU0 = BF(4 + c, tu), bU1 = BF(4 + c, tu + 1);
        short8 bF0 = BF(4 + c, tf), bF1 = BF(4 + c, tf + 1);
        short8 aH0 = AF(1, c, 0), aH1 = AF(1, c, 1);
        short8 aL0 = AF(2, c, 0), aL1 = AF(2, c, 1);
        short8 aR0 = AF(3, c, 0), aR1 = AF(3, c, 1);
        MM(accI[0][0], aH0, bI0); MM(accI[0][1], aH0, bI1);
        MM(accI[1][0], aH1, bI0); MM(accI[1][1], aH1, bI1);
        MM(accO[0][0], aH0, bO0); MM(accO[0][1], aH0, bO1);
        MM(accO[1][0], aH1, bO0); MM(accO[1][1], aH1, bO1);
        MM(accU[0][0], aH0, bU0); MM(accU[0][1], aH0, bU1);
        MM(accU[1][0], aH1, bU0); MM(accU[1][1], aH1, bU1);
        MM(accFl[0][0], aL0, bF0); MM(accFl[0][1], aL0, bF1);
        MM(accFl[1][0], aL1, bF0); MM(accFl[1][1], aL1, bF1);
        MM(accFr[0][0], aR0, bF0); MM(accFr[0][1], aR0, bF1);
        MM(accFr[1][0], aR1, bF0); MM(accFr[1][1], aR1, bF1);
    }
#undef BF
#undef AF

    __syncthreads();                 // all A_s reads done; reuse as f32 h_s
    float* h_s = (float*)A_s;        // 32 x 132 f32

    #pragma unroll
    for (int rt = 0; rt < 2; ++rt) {
        #pragma unroll
        for (int jt = 0; jt < 2; ++jt) {
            const int col = w * 32 + jt * 16 + ln;
            const float bib = biou[col], bob = biou[128 + col], bub = biou[256 + col];
            const float bfb = bfv[col];
            #pragma unroll
            for (int r = 0; r < 4; ++r) {
                const int row = rt * 16 + q * 4 + r;
                const int g = g0p + row;
                const float iv = accI[rt][jt][r] + bib;
                const float ov = accO[rt][jt][r] + bob;
                const float uv = accU[rt][jt][r] + bub;
                const float fl = sigm_(accFl[rt][jt][r] + bfb);
                const float fr = sigm_(accFr[rt][jt][r] + bfb);
                const float fc = fl * bf2f(c_lds[2 * row][col]) + fr * bf2f(c_lds[2 * row + 1][col]);
                const float cv = sigm_(iv) * tanh_(uv) + fc;
                const float hv = sigm_(ov) * tanh_(cv);
                c_ws[(size_t)g * 128 + col] = cv;
                hB[(size_t)g * 128 + col] = f2bf(hv);
                h_s[row * 132 + col] = hv;
            }
        }
    }
    __syncthreads();
    if (t < 160) {                   // parent out-head
        const int n = t / 5, cc5 = t - 5 * n;
        float acc = bout[cc5];
        const float* hp = &h_s[n * 132];
        const float* wp = &wout_t[cc5 * 132];
        #pragma unroll 4
        for (int k4 = 0; k4 < 32; ++k4) {
            float4 hv = *(const float4*)(hp + 4 * k4);
            float4 wv = *(const float4*)(wp + 4 * k4);
            acc += hv.x * wv.x + hv.y * wv.y + hv.z * wv.z + hv.w * wv.w;
        }
        outp[(size_t)(g0p + n) * 5 + cc5] = acc;
    }
}

// ---------------------------------------------------------------------------
// Big-level MFMA kernel (d = 15..10): lb(256,2) — R15's (256,3) regressed
// ~2.5% (clp/crp prefetch regs push natural usage past the 170 cap ->
// spills; natural allocation already admits 3 waves/SIMD at 168 regs).
// ---------------------------------------------------------------------------
template<int HC>
__global__ __launch_bounds__(256, 2) void tree_level_mfma(
    const int* __restrict__ xids, const int* __restrict__ msk,
    const unsigned short* __restrict__ embB, const unsigned short* __restrict__ bpack,
    const float* __restrict__ biou, const float* __restrict__ bfv,
    const float* __restrict__ Wout, const float* __restrict__ bout,
    unsigned short* __restrict__ hB, float* __restrict__ c_ws, float* __restrict__ outp,
    int s0)
{
    __shared__ __align__(16) unsigned short A_s[16384];   // 4 x 4096, 32 KB
    __shared__ __align__(16) float wout_t[660];           // [5][132] transposed, padded

    const int t  = threadIdx.x;
    const int g0 = s0 + blockIdx.x * 32;

    if (t < 160) {   // load + transpose Wout (row-major [k][5] -> [c][132])
        float4 v = ((const float4*)Wout)[t];
        const int e0 = 4 * t;
        wout_t[((e0    ) % 5) * 132 + (e0    ) / 5] = v.x;
        wout_t[((e0 + 1) % 5) * 132 + (e0 + 1) / 5] = v.y;
        wout_t[((e0 + 2) % 5) * 132 + (e0 + 2) / 5] = v.z;
        wout_t[((e0 + 3) % 5) * 132 + (e0 + 3) / 5] = v.w;
    }

    {   // ---- stage emb (region 0) ----
        const int n = t >> 3, seg = t & 7;
        const int g = g0 + n;
        const int ei = xids[g] * msk[g];
        const uint4* es = (const uint4*)(embB + (size_t)ei * 128 + seg * 16);
        uint4 e0 = es[0], e1 = es[1];
        const int cc = seg >> 1, q0 = (seg & 1) * 2;
        *(uint4*)&A_s[(cc * 4 + q0) * 256 + n * 8]       = e0;
        *(uint4*)&A_s[(cc * 4 + q0 + 1) * 256 + n * 8]   = e1;
        if (HC) {    // ---- stage h_l / h_r (regions 2,3) ----
            const int row = t >> 2, qt = t & 3;
            const int child = 2 * g0 + 1 + row;
            const int m = row >> 1, reg = 2 + (row & 1);
            const uint4* hp = (const uint4*)(hB + (size_t)child * 128 + qt * 32);
            uint4 p0 = hp[0], p1 = hp[1], p2 = hp[2], p3 = hp[3];
            unsigned short* base = &A_s[reg * 4096 + qt * 1024 + m * 8];
            *(uint4*)(base)       = p0;
            *(uint4*)(base + 256) = p1;
            *(uint4*)(base + 512) = p2;
            *(uint4*)(base + 768) = p3;
        }
    }

    const int lane = t & 63, w = t >> 6;
    const int ln = lane & 15, q = lane >> 4;

    // ---- prefetch child c cells for the epilogue (fire-and-forget) ----
    float clp[2][2][4], crp[2][2][4];
    if (HC) {
        #pragma unroll
        for (int rt = 0; rt < 2; ++rt)
            #pragma unroll
            for (int jt = 0; jt < 2; ++jt) {
                const int col = w * 32 + jt * 16 + ln;
                #pragma unroll
                for (int r = 0; r < 4; ++r) {
                    const int g = g0 + rt * 16 + q * 4 + r;
                    clp[rt][jt][r] = c_ws[(size_t)(2 * g + 1) * 128 + col];
                    crp[rt][jt][r] = c_ws[(size_t)(2 * g + 2) * 128 + col];
                }
            }
    }

    if (HC) {        // ---- h_sum = h_l + h_r (region 1), in-LDS ----
        __syncthreads();
        const int m = t >> 3, seg = t & 7;
        const int cc = seg >> 1, q0 = (seg & 1) * 2;
        #pragma unroll
        for (int u = 0; u < 2; ++u) {
            const int idx = (cc * 4 + q0 + u) * 256 + m * 8;
            short8 l = *(short8*)&A_s[2 * 4096 + idx];
            short8 r = *(short8*)&A_s[3 * 4096 + idx];
            short8 s;
            #pragma unroll
            for (int j = 0; j < 8; ++j)
                s[j] = (short)f2bf(bf2f((unsigned short)l[j]) + bf2f((unsigned short)r[j]));
            *(short8*)&A_s[4096 + idx] = s;
        }
    }
    __syncthreads();

    const unsigned short* bp = bpack + ln * 32 + q * 8;     // + c*16384 + tile*512
    const unsigned short* ap = A_s + q * 256 + ln * 8;      // + r*4096 + cc*1024 + rt*128

#define BF(c, tile) (*(const short8*)(bp + (c) * 16384 + (tile) * 512))
#define AF(r, cc, rt) (*(const short8*)(ap + (r) * 4096 + (cc) * 1024 + (rt) * 128))

    f32x4 accI[2][2] = {}, accO[2][2] = {}, accU[2][2] = {}, accFl[2][2] = {}, accFr[2][2] = {};
    const int ti = 2 * w, to = 8 + 2 * w, tu = 16 + 2 * w, tf = 24 + 2 * w;

    #pragma unroll
    for (int c = 0; c < 4; ++c) {      // emb chunks
        short8 bI0 = BF(c, ti), bI1 = BF(c, ti + 1);
        short8 bO0 = BF(c, to), bO1 = BF(c, to + 1);
        short8 bU0 = BF(c, tu), bU1 = BF(c, tu + 1);
        short8 aE0 = AF(0, c, 0), aE1 = AF(0, c, 1);
        MM(accI[0][0], aE0, bI0); MM(accI[0][1], aE0, bI1);
        MM(accI[1][0], aE1, bI0); MM(accI[1][1], aE1, bI1);
        MM(accO[0][0], aE0, bO0); MM(accO[0][1], aE0, bO1);
        MM(accO[1][0], aE1, bO0); MM(accO[1][1], aE1, bO1);
        MM(accU[0][0], aE0, bU0); MM(accU[0][1], aE0, bU1);
        MM(accU[1][0], aE1, bU0); MM(accU[1][1], aE1, bU1);
        if (HC) {
            short8 bF0 = BF(c, tf), bF1 = BF(c, tf + 1);
            MM(accFl[0][0], aE0, bF0); MM(accFl[0][1], aE0, bF1);
            MM(accFl[1][0], aE1, bF0); MM(accFl[1][1], aE1, bF1);
        }
    }
    if (HC) {
        #pragma unroll
        for (int rt = 0; rt < 2; ++rt)
            #pragma unroll
            for (int jt = 0; jt < 2; ++jt)
                accFr[rt][jt] = accFl[rt][jt];      // fork shared x_f
        #pragma unroll
        for (int c = 0; c < 4; ++c) {  // h chunks (bpack chunk 4+c)
            short8 bI0 = BF(4 + c, ti), bI1 = BF(4 + c, ti + 1);
            short8 bO0 = BF(4 + c, to), bO1 = BF(4 + c, to + 1);
            short8 bU0 = BF(4 + c, tu), bU1 = BF(4 + c, tu + 1);
            short8 bF0 = BF(4 + c, tf), bF1 = BF(4 + c, tf + 1);
            short8 aH0 = AF(1, c, 0), aH1 = AF(1, c, 1);
            short8 aL0 = AF(2, c, 0), aL1 = AF(2, c, 1);
            short8 aR0 = AF(3, c, 0), aR1 = AF(3, c, 1);
            MM(accI[0][0], aH0, bI0); MM(accI[0][1], aH0, bI1);
            MM(accI[1][0], aH1, bI0); MM(accI[1][1], aH1, bI1);
            MM(accO[0][0], aH0, bO0); MM(accO[0][1], aH0, bO1);
            MM(accO[1][0], aH1, bO0); MM(accO[1][1], aH1, bO1);
            MM(accU[0][0], aH0, bU0); MM(accU[0][1], aH0, bU1);
            MM(accU[1][0], aH1, bU0); MM(accU[1][1], aH1, bU1);
            MM(accFl[0][0], aL0, bF0); MM(accFl[0][1], aL0, bF1);
            MM(accFl[1][0], aL1, bF0); MM(accFl[1][1], aL1, bF1);
            MM(accFr[0][0], aR0, bF0); MM(accFr[0][1], aR0, bF1);
            MM(accFr[1][0], aR1, bF0); MM(accFr[1][1], aR1, bF1);
        }
    }
#undef BF
#undef AF

    __syncthreads();                 // all A_s reads done; reuse as f32 h_s
    float* h_s = (float*)A_s;        // 32 x 132 f32 (16.9 KB <= 32 KB)

    #pragma unroll
    for (int rt = 0; rt < 2; ++rt) {
        #pragma unroll
        for (int jt = 0; jt < 2; ++jt) {
            const int col = w * 32 + jt * 16 + ln;
            const float bib = biou[col], bob = biou[128 + col], bub = biou[256 + col];
            const float bfb = bfv[col];
            #pragma unroll
            for (int r = 0; r < 4; ++r) {
                const int row = rt * 16 + q * 4 + r;
                const int g = g0 + row;
                const float iv = accI[rt][jt][r] + bib;
                const float ov = accO[rt][jt][r] + bob;
                const float uv = accU[rt][jt][r] + bub;
                float fc = 0.f;
                if (HC) {
                    const float fl = sigm_(accFl[rt][jt][r] + bfb);
                    const float fr = sigm_(accFr[rt][jt][r] + bfb);
                    fc = fl * clp[rt][jt][r] + fr * crp[rt][jt][r];
                }
                const float cc = sigm_(iv) * tanh_(uv) + fc;
                const float hh = sigm_(ov) * tanh_(cc);
                c_ws[(size_t)g * 128 + col] = cc;
                hB[(size_t)g * 128 + col] = f2bf(hh);
                h_s[row * 132 + col] = hh;
            }
        }
    }
    __syncthreads();
    if (t < 160) {                   // output head: 32 nodes x 5 cols, f32, b128 reads
        const int n = t / 5, cc5 = t - 5 * n;
        float acc = bout[cc5];
        const float* hp = &h_s[n * 132];
        const float* wp = &wout_t[cc5 * 132];
        #pragma unroll 4
        for (int k4 = 0; k4 < 32; ++k4) {
            float4 hv = *(const float4*)(hp + 4 * k4);
            float4 wv = *(const float4*)(wp + 4 * k4);
            acc += hv.x * wv.x + hv.y * wv.y + hv.z * wv.z + hv.w * wv.w;
        }
        outp[(size_t)(g0 + n) * 5 + cc5] = acc;
    }
}

// ---------------------------------------------------------------------------
// Subtree kernel: unchanged verified structure.
// ---------------------------------------------------------------------------
__global__ __launch_bounds__(256) void tree_subtree(
    const int* __restrict__ xids, const int* __restrict__ msk,
    const unsigned short* __restrict__ embB, const unsigned short* __restrict__ bpack,
    const float* __restrict__ biou, const float* __restrict__ bfv,
    const float* __restrict__ Wout, const float* __restrict__ bout,
    unsigned short* __restrict__ hB, float* __restrict__ c_ws, float* __restrict__ outp,
    int dTop, int dBot)
{
    __shared__ __align__(16) unsigned short A_s[6144];    // 3 x 2048, 12 KB
    __shared__ __align__(16) float cbuf[2][16][128];      // 16 KB
    __shared__ __align__(16) float wout_t[5][132];        // transposed, padded

    const int t = threadIdx.x, b = blockIdx.x;
    const int lane = t & 63, w = t >> 6;
    const int ln = lane & 15, q = lane >> 4;

    if (t < 160) {   // load + transpose Wout
        float4 v = ((const float4*)Wout)[t];
        const int e0 = 4 * t;
        wout_t[(e0    ) % 5][(e0    ) / 5] = v.x;
        wout_t[(e0 + 1) % 5][(e0 + 1) / 5] = v.y;
        wout_t[(e0 + 2) % 5][(e0 + 2) / 5] = v.z;
        wout_t[(e0 + 3) % 5][(e0 + 3) / 5] = v.w;
    }

    const int col0 = w * 32 + ln, col1 = col0 + 16;
    const float bib0 = biou[col0], bob0 = biou[128 + col0], bub0 = biou[256 + col0], bfb0 = bfv[col0];
    const float bib1 = biou[col1], bob1 = biou[128 + col1], bub1 = biou[256 + col1], bfb1 = bfv[col1];

    const unsigned short* bp = bpack + ln * 32 + q * 8;
    const unsigned short* ap = A_s + (q * 16 + ln) * 8;
    const int ti = 2 * w, to = 8 + 2 * w, tu = 16 + 2 * w, tf = 24 + 2 * w;

    for (int d = dTop; d >= dBot; --d) {
        const int nd = 1 << (d - dBot);
        const int g0 = ((1 << d) - 1) + (b << (d - dBot));
        const int par = (dTop - d) & 1;

        if (t < 128) {   // stage emb (region 0), 16 rows (garbage rows >= nd ok)
            const int m = t >> 3, seg = t & 7;
            const int g = g0 + m;
            const int ei = xids[g] * msk[g];
            const uint4* es = (const uint4*)(embB + (size_t)ei * 128 + seg * 16);
            uint4 e0 = es[0], e1 = es[1];
            const int cc = seg >> 1, q0 = (seg & 1) * 2;
            *(uint4*)&A_s[cc * 512 + (q0 * 16 + m) * 8]       = e0;
            *(uint4*)&A_s[cc * 512 + ((q0 + 1) * 16 + m) * 8] = e1;
        }
        if (d == dTop) {   // stage 32 child h rows from global
            const int row = t >> 3, sg = t & 7;
            const int child = 2 * g0 + 1 + row;
            const uint4* hp = (const uint4*)(hB + (size_t)child * 128 + sg * 16);
            uint4 h0 = hp[0], h1 = hp[1];
            const int reg = 1 + (row & 1), mm = row >> 1;
            const int cc = sg >> 1, q0 = (sg & 1) * 2;
            *(uint4*)&A_s[reg * 2048 + cc * 512 + (q0 * 16 + mm) * 8]       = h0;
            *(uint4*)&A_s[reg * 2048 + cc * 512 + ((q0 + 1) * 16 + mm) * 8] = h1;
        }
        __syncthreads();

        f32x4 accI[2] = {}, accO[2] = {}, accU[2] = {}, accFl[2] = {}, accFr[2] = {};
#define BF1(c, tile) (*(const short8*)(bp + (c) * 16384 + (tile) * 512))
#define AF1(r, c) (*(const short8*)(ap + (r) * 2048 + (c) * 512))
        #pragma unroll
        for (int c = 0; c < 4; ++c) {
            short8 aE = AF1(0, c);
            MM(accI[0], aE, BF1(c, ti)); MM(accI[1], aE, BF1(c, ti + 1));
            MM(accO[0], aE, BF1(c, to)); MM(accO[1], aE, BF1(c, to + 1));
            MM(accU[0], aE, BF1(c, tu)); MM(accU[1], aE, BF1(c, tu + 1));
            MM(accFl[0], aE, BF1(c, tf)); MM(accFl[1], aE, BF1(c, tf + 1));
        }
        accFr[0] = accFl[0]; accFr[1] = accFl[1];
        #pragma unroll
        for (int c = 0; c < 4; ++c) {
            short8 aL = AF1(1, c), aR = AF1(2, c);
            short8 bI0 = BF1(4 + c, ti), bI1 = BF1(4 + c, ti + 1);
            short8 bO0 = BF1(4 + c, to), bO1 = BF1(4 + c, to + 1);
            short8 bU0 = BF1(4 + c, tu), bU1 = BF1(4 + c, tu + 1);
            short8 bF0 = BF1(4 + c, tf), bF1 = BF1(4 + c, tf + 1);
            MM(accI[0], aL, bI0); MM(accI[0], aR, bI0);
            MM(accI[1], aL, bI1); MM(accI[1], aR, bI1);
            MM(accO[0], aL, bO0); MM(accO[0], aR, bO0);
            MM(accO[1], aL, bO1); MM(accO[1], aR, bO1);
            MM(accU[0], aL, bU0); MM(accU[0], aR, bU0);
            MM(accU[1], aL, bU1); MM(accU[1], aR, bU1);
            MM(accFl[0], aL, bF0); MM(accFl[1], aL, bF1);
            MM(accFr[0], aR, bF0); MM(accFr[1], aR, bF1);
        }
#undef BF1
#undef AF1
        __syncthreads();   // k-loop reads done before epilogue overwrites A_s h

        #pragma unroll
        for (int jt = 0; jt < 2; ++jt) {
            const int col = jt ? col1 : col0;
            const float bib = jt ? bib1 : bib0, bob = jt ? bob1 : bob0;
            const float bub = jt ? bub1 : bub0, bfb = jt ? bfb1 : bfb0;
            const f32x4 aI = accI[jt], aO = accO[jt], aU = accU[jt];
            const f32x4 aFl = accFl[jt], aFr = accFr[jt];
            #pragma unroll
            for (int r = 0; r < 4; ++r) {
                const int row = q * 4 + r;
                const int g = g0 + row;
                float cl, cr;
                if (d == dTop) {
                    cl = c_ws[(size_t)(2 * g + 1) * 128 + col];
                    cr = c_ws[(size_t)(2 * g + 2) * 128 + col];
                } else {
                    cl = cbuf[1 - par][2 * row][col];
                    cr = cbuf[1 - par][2 * row + 1][col];
                }
                const float iv = aI[r] + bib;
                const float ov = aO[r] + bob;
                const float uv = aU[r] + bub;
                const float fl = sigm_(aFl[r] + bfb);
                const float fr = sigm_(aFr[r] + bfb);
                const float cc = sigm_(iv) * tanh_(uv) + fl * cl + fr * cr;
                const float hh = sigm_(ov) * tanh_(cc);
                cbuf[par][row][col] = cc;
                const unsigned short hb = f2bf(hh);
                const int reg = 1 + (row & 1), mm = row >> 1;
                A_s[reg * 2048 + (col >> 5) * 512 + ((((col >> 3) & 3) * 16) + mm) * 8 + (col & 7)] = hb;
                if (row < nd) {
                    c_ws[(size_t)g * 128 + col] = cc;
                    hB[(size_t)g * 128 + col] = hb;
                }
            }
        }
        __syncthreads();
        if (t < nd * 5) {            // output head: b128 octet reads of fragment h
            const int n = t / 5, cc5 = t - 5 * n;
            const int reg = 1 + (n & 1), mm = n >> 1;
            float acc = bout[cc5];
            const unsigned short* hbase = &A_s[reg * 2048 + mm * 8];
            const float* wp = wout_t[cc5];
            #pragma unroll
            for (int oct = 0; oct < 16; ++oct) {
                short8 hv = *(const short8*)(hbase + (oct >> 2) * 512 + (oct & 3) * 128);
                const float* wo = wp + oct * 8;
                float4 w0 = *(const float4*)(wo);
                float4 w1 = *(const float4*)(wo + 4);
                acc += bf2f((unsigned short)hv[0]) * w0.x + bf2f((unsigned short)hv[1]) * w0.y
                     + bf2f((unsigned short)hv[2]) * w0.z + bf2f((unsigned short)hv[3]) * w0.w
                     + bf2f((unsigned short)hv[4]) * w1.x + bf2f((unsigned short)hv[5]) * w1.y
                     + bf2f((unsigned short)hv[6]) * w1.z + bf2f((unsigned short)hv[7]) * w1.w;
            }
            outp[(size_t)(g0 + n) * 5 + cc5] = acc;
        }
        __syncthreads();
    }
}
#undef MM

extern "C" void kernel_launch(void* const* d_in, const int* in_sizes, int n_in,
                              void* d_out, int out_size, void* d_ws, size_t ws_size,
                              hipStream_t stream)
{
    (void)in_sizes; (void)n_in; (void)out_size; (void)ws_size;
    const int*   xids = (const int*)d_in[0];
    const int*   msk  = (const int*)d_in[1];
    const float* emb  = (const float*)d_in[2];
    const float* Wiou = (const float*)d_in[3];
    const float* Uiou = (const float*)d_in[4];
    const float* biou = (const float*)d_in[5];
    const float* Wf   = (const float*)d_in[6];
    const float* Uf   = (const float*)d_in[7];
    const float* bfv  = (const float*)d_in[8];
    const float* Wout = (const float*)d_in[9];
    const float* bout = (const float*)d_in[10];
    float* outp = (float*)d_out;

    // workspace: embB (8.2MB) | bpack (0.26MB) | hB (67MB) | c_ws f32 (134MB)
    unsigned short* embB  = (unsigned short*)d_ws;
    unsigned short* bpack = embB + (size_t)32000 * 128;
    unsigned short* hB    = bpack + 131072;
    float*          c_ws  = (float*)(hB + (size_t)NN * 128);

    cvt_emb<<<dim3((32000 * 128 / 4 + 255) / 256), dim3(256), 0, stream>>>(emb, embB, 32000 * 128 / 4);
    build_bpack<<<dim3(131072 / 256), dim3(256), 0, stream>>>(Wiou, Uiou, Wf, Uf, bpack);

    // fused leaf (d17) + d16: leaf h/c stay in LDS, no global round-trip
    tree_leaf16_fused<<<dim3(2048), dim3(256), 0, stream>>>(
        xids, msk, embB, bpack, biou, bfv, Wout, bout, hB, c_ws, outp);

    for (int d = DEPTH - 3; d >= 10; --d) {
        const int s0 = (1 << d) - 1;
        tree_level_mfma<1><<<dim3((1 << d) / 32), dim3(256), 0, stream>>>(
            xids, msk, embB, bpack, biou, bfv, Wout, bout, hB, c_ws, outp, s0);
    }
    // levels 9..5: 32 subtree blocks; levels 4..0: 1 subtree block
    tree_subtree<<<dim3(32), dim3(256), 0, stream>>>(
        xids, msk, embB, bpack, biou, bfv, Wout, bout, hB, c_ws, outp, 9, 5);
    tree_subtree<<<dim3(1), dim3(256), 0, stream>>>(
        xids, msk, embB, bpack, biou, bfv, Wout, bout, hB, c_ws, outp, 4, 0);
}